// Round 1
// baseline (54.585 us; speedup 1.0000x reference)
//
#include <hip/hip_runtime.h>
#include <math.h>

#define TWO_PI_F 6.28318530717958647692f

// ---------------------------------------------------------------------------
// Kernel 1: precompute per-index projections.
//   A[i,h] = c0[h] + pe(s_i) @ W1[0:4, h]   (c0 = b1 + z_g @ W1[10:42])
//   B[i,h] = pe(s_i) @ W1[4:8, h]
// Stored transposed+tiled: X_t[i>>5][h][i&31]  (64 blocks x 64 h x 32 i)
// so the main kernel stages with coalesced global reads AND conflict-free
// LDS writes/reads. Also stores cs[i]=cos(2*pi*s_i), sn[i]=sin(2*pi*s_i).
// ---------------------------------------------------------------------------
__global__ void gd_precomp(const float* __restrict__ z,
                           const float* __restrict__ s,
                           const float* __restrict__ W1,
                           const float* __restrict__ b1,
                           float* __restrict__ A_t,
                           float* __restrict__ B_t,
                           float* __restrict__ cs,
                           float* __restrict__ sn,
                           int N) {
    int gid = blockIdx.x * blockDim.x + threadIdx.x;
    if (gid >= N * 64) return;
    int i = gid >> 6;
    int h = gid & 63;

    float sv  = s[i];
    float ang = TWO_PI_F * sv;
    float c1  = cosf(ang);
    float s1  = sinf(ang);
    // k=2 harmonic via double-angle (exact identity)
    float c2 = c1 * c1 - s1 * s1;
    float s2 = 2.0f * c1 * s1;

    // constant (z, b1) part
    float c0 = b1[h];
#pragma unroll
    for (int zz = 0; zz < 32; ++zz)
        c0 = fmaf(z[zz], W1[(10 + zz) * 64 + h], c0);

    float A = c0;
    A = fmaf(c1, W1[0 * 64 + h], A);
    A = fmaf(s1, W1[1 * 64 + h], A);
    A = fmaf(c2, W1[2 * 64 + h], A);
    A = fmaf(s2, W1[3 * 64 + h], A);

    float B = 0.0f;
    B = fmaf(c1, W1[4 * 64 + h], B);
    B = fmaf(s1, W1[5 * 64 + h], B);
    B = fmaf(c2, W1[6 * 64 + h], B);
    B = fmaf(s2, W1[7 * 64 + h], B);

    int blk = i >> 5;
    int il  = i & 31;
    A_t[blk * 2048 + h * 32 + il] = A;
    B_t[blk * 2048 + h * 32 + il] = B;
    if (h == 0) { cs[i] = c1; sn[i] = s1; }
}

// ---------------------------------------------------------------------------
// Kernel 2: 32x32 output tiles, upper-triangular blocks only.
// Per element computes BOTH orientations (they share the diff term) and
// averages -> symmetrized result directly. Transposed tile written through
// padded LDS so both global writes are coalesced.
// ---------------------------------------------------------------------------
__global__ __launch_bounds__(256) void gd_main(
    const float* __restrict__ A_t, const float* __restrict__ B_t,
    const float* __restrict__ cs,  const float* __restrict__ sn,
    const float* __restrict__ W1,  const float* __restrict__ W2,
    const float* __restrict__ b2v, float* __restrict__ out, int N) {
    int bi = blockIdx.y;
    int bj = blockIdx.x;
    if (bj < bi) return;  // block-uniform early exit

    __shared__ float sAi[64][32], sBi[64][32], sAj[64][32], sBj[64][32];
    __shared__ float sW2[64], sWc[64], sWs[64];
    __shared__ float scsi[32], ssni[32], scsj[32], ssnj[32];
    __shared__ float tile[32][33];  // +1 pad: conflict-free transpose

    int t = threadIdx.x;

    // stage A/B tiles (coalesced global, conflict-free LDS)
    const float* gAi = A_t + (size_t)bi * 2048;
    const float* gBi = B_t + (size_t)bi * 2048;
    const float* gAj = A_t + (size_t)bj * 2048;
    const float* gBj = B_t + (size_t)bj * 2048;
#pragma unroll
    for (int r = 0; r < 8; ++r) {
        int idx = t + r * 256;
        ((float*)sAi)[idx] = gAi[idx];
        ((float*)sBi)[idx] = gBi[idx];
        ((float*)sAj)[idx] = gAj[idx];
        ((float*)sBj)[idx] = gBj[idx];
    }
    if (t < 64) {
        sW2[t] = W2[t];
        sWc[t] = W1[8 * 64 + t];
        sWs[t] = W1[9 * 64 + t];
    }
    if (t < 32) {
        scsi[t] = cs[bi * 32 + t];
        ssni[t] = sn[bi * 32 + t];
        scsj[t] = cs[bj * 32 + t];
        ssnj[t] = sn[bj * 32 + t];
    }
    __syncthreads();

    int tj  = t & 31;   // local j (lanes consecutive -> coalesced writes)
    int ti0 = t >> 5;   // local i base; rows il = ti0 + 8*r, r=0..3

    float cj = scsj[tj], sj = ssnj[tj];
    float ct[4], st[4];
    float acc1[4] = {0.f, 0.f, 0.f, 0.f};
    float acc2[4] = {0.f, 0.f, 0.f, 0.f};
#pragma unroll
    for (int r = 0; r < 4; ++r) {
        int il = ti0 + 8 * r;
        float ci = scsi[il], si = ssni[il];
        // cos/sin of 2*pi*circdist(s_i, s_j) without trig:
        ct[r] = fmaf(ci, cj, si * sj);
        st[r] = fabsf(fmaf(si, cj, -(ci * sj)));
    }

#pragma unroll 4
    for (int h = 0; h < 64; ++h) {
        float w2  = sW2[h];
        float wc  = sWc[h];
        float ws  = sWs[h];
        float aj  = sAj[h][tj];
        float bjv = sBj[h][tj];
#pragma unroll
        for (int r = 0; r < 4; ++r) {
            int il = ti0 + 8 * r;
            float d  = fmaf(ct[r], wc, st[r] * ws);
            float p1 = sAi[h][il] + bjv + d;   // orientation (i,j)
            float p2 = aj + sBi[h][il] + d;    // orientation (j,i)
            acc1[r] = fmaf(fmaxf(p1, 0.f), w2, acc1[r]);
            acc2[r] = fmaf(fmaxf(p2, 0.f), w2, acc2[r]);
        }
    }

    float b2 = b2v[0];
#pragma unroll
    for (int r = 0; r < 4; ++r) {
        int il = ti0 + 8 * r;
        int gi = bi * 32 + il;
        int gj = bj * 32 + tj;
        float v = 0.5f * (acc1[r] + acc2[r]) + b2;
        if (gi == gj) v = -1e9f;
        out[(size_t)gi * N + gj] = v;
        tile[il][tj] = v;
    }

    if (bj > bi) {  // mirror block: coalesced transposed write via LDS
        __syncthreads();
#pragma unroll
        for (int r = 0; r < 4; ++r) {
            int jl = ti0 + 8 * r;
            int grow = bj * 32 + jl;   // output row = j
            int gcol = bi * 32 + tj;   // output col = i
            out[(size_t)grow * N + gcol] = tile[tj][jl];
        }
    }
}

extern "C" void kernel_launch(void* const* d_in, const int* in_sizes, int n_in,
                              void* d_out, int out_size, void* d_ws, size_t ws_size,
                              hipStream_t stream) {
    const float* z  = (const float*)d_in[0];  // [32]
    const float* s  = (const float*)d_in[1];  // [N]
    const float* W1 = (const float*)d_in[2];  // [42,64]
    const float* b1 = (const float*)d_in[3];  // [64]
    const float* W2 = (const float*)d_in[4];  // [64]
    const float* b2 = (const float*)d_in[5];  // [1]
    int N = in_sizes[1];                      // 2048

    float* A_t = (float*)d_ws;                // N*64 floats
    float* B_t = A_t + (size_t)N * 64;        // N*64 floats
    float* cs  = B_t + (size_t)N * 64;        // N floats
    float* sn  = cs + N;                      // N floats

    float* out = (float*)d_out;

    int pre_threads = N * 64;
    gd_precomp<<<(pre_threads + 255) / 256, 256, 0, stream>>>(
        z, s, W1, b1, A_t, B_t, cs, sn, N);

    int NB = N / 32;
    dim3 grid(NB, NB);
    gd_main<<<grid, 256, 0, stream>>>(A_t, B_t, cs, sn, W1, W2, b2, out, N);
}

// Round 2
// 44.611 us; speedup vs baseline: 1.2236x; 1.2236x over previous
//
#include <hip/hip_runtime.h>
#include <math.h>

#define TWO_PI_F 6.28318530717958647692f
typedef float f4 __attribute__((ext_vector_type(4)));

// ---------------------------------------------------------------------------
// Kernel 1: per-index projections, written in a SWIZZLED global layout so the
// main kernel's LDS staging is a linear copy and its b128 reads are
// bank-conflict-free.
//   A[i,h] = zc[h] + pe(s_i) @ W1[0:4, h]   (zc = b1 + z_g @ W1[10:42])
//   B[i,h] = pe(s_i) @ W1[4:8, h]
// Layout: X2[i>>5][il][h ^ ((il&7)<<2)], il = i&31.  Also cs/sn = cos/sin(2*pi*s).
// ---------------------------------------------------------------------------
__global__ __launch_bounds__(256) void gd_precomp(
    const float* __restrict__ z,  const float* __restrict__ s,
    const float* __restrict__ W1, const float* __restrict__ b1,
    float* __restrict__ A2, float* __restrict__ B2,
    float* __restrict__ cs, float* __restrict__ sn, int N)
{
    __shared__ float zc[64];
    int t = threadIdx.x;
    if (t < 64) {
        float acc = b1[t];
#pragma unroll
        for (int zz = 0; zz < 32; ++zz)
            acc = fmaf(z[zz], W1[(10 + zz) * 64 + t], acc);
        zc[t] = acc;
    }
    __syncthreads();

    int gid = blockIdx.x * 256 + t;
    if (gid >= N * 64) return;
    int i = gid >> 6;
    int h = gid & 63;

    float sv = s[i];
    float s1, c1;
    sincosf(TWO_PI_F * sv, &s1, &c1);
    float c2 = c1 * c1 - s1 * s1;   // exact double-angle for k=2
    float s2 = 2.0f * c1 * s1;

    float A = zc[h];
    A = fmaf(c1, W1[0 * 64 + h], A);
    A = fmaf(s1, W1[1 * 64 + h], A);
    A = fmaf(c2, W1[2 * 64 + h], A);
    A = fmaf(s2, W1[3 * 64 + h], A);

    float B = 0.0f;
    B = fmaf(c1, W1[4 * 64 + h], B);
    B = fmaf(s1, W1[5 * 64 + h], B);
    B = fmaf(c2, W1[6 * 64 + h], B);
    B = fmaf(s2, W1[7 * 64 + h], B);

    int blk = i >> 5;
    int il  = i & 31;
    int col = h ^ ((il & 7) << 2);        // XOR swizzle in GLOBAL layout
    A2[blk * 2048 + il * 64 + col] = A;
    B2[blk * 2048 + il * 64 + col] = B;
    if (h == 0) { cs[i] = c1; sn[i] = s1; }
}

// ---------------------------------------------------------------------------
// Kernel 2: one 32x32 tile per block, upper-triangular blocks only (1D grid,
// triangular decode). Each thread owns 4 i-rows x 1 j-col, computes BOTH
// orientations (shared diff-term), writes symmetrized value + mirrored tile.
// All hot LDS reads are b128 with immediate offsets; weights are b128
// broadcasts; swizzle constant is per-thread ((ti0+8r)&7 == ti0&7).
// ---------------------------------------------------------------------------
__global__ __launch_bounds__(256, 4) void gd_main(
    const float* __restrict__ A2, const float* __restrict__ B2,
    const float* __restrict__ cs, const float* __restrict__ sn,
    const float* __restrict__ W1, const float* __restrict__ W2,
    const float* __restrict__ b2v, float* __restrict__ out, int N, int NB)
{
    __shared__ __attribute__((aligned(16))) float sAB[4][32][64]; // Ai,Bi,Aj,Bj
    __shared__ __attribute__((aligned(16))) float sWc[64];
    __shared__ __attribute__((aligned(16))) float sWs[64];
    __shared__ __attribute__((aligned(16))) float sW2[64];
    __shared__ float scsi[32], ssni[32], scsj[32], ssnj[32];
    __shared__ float tile[32][33];

    // --- triangular block decode: u -> (bi, bj), bj >= bi ---
    int u = blockIdx.x;
    int M = 2 * NB + 1;
    float disc = (float)(M * M - 8 * u);
    int bi = (int)(((float)M - sqrtf(disc)) * 0.5f);
    if (bi < 0) bi = 0;
    if (bi > NB - 1) bi = NB - 1;
    while (bi > 0 && bi * (M - bi) / 2 > u) --bi;
    while ((bi + 1) * (M - (bi + 1)) / 2 <= u) ++bi;
    int bj = bi + (u - bi * (M - bi) / 2);

    int t = threadIdx.x;

    // --- staging: linear conflict-free copies (layout pre-swizzled) ---
    {
        const f4* g0 = (const f4*)(A2 + (size_t)bi * 2048);
        const f4* g1 = (const f4*)(B2 + (size_t)bi * 2048);
        const f4* g2 = (const f4*)(A2 + (size_t)bj * 2048);
        const f4* g3 = (const f4*)(B2 + (size_t)bj * 2048);
        f4* d = (f4*)&sAB[0][0][0];
        d[t]        = g0[t];
        d[t + 256]  = g0[t + 256];
        d[t + 512]  = g1[t];
        d[t + 768]  = g1[t + 256];
        d[t + 1024] = g2[t];
        d[t + 1280] = g2[t + 256];
        d[t + 1536] = g3[t];
        d[t + 1792] = g3[t + 256];
    }
    if (t < 64) {
        sWc[t] = W1[8 * 64 + t];
        sWs[t] = W1[9 * 64 + t];
        sW2[t] = W2[t];
    }
    if (t < 32) {
        scsi[t] = cs[bi * 32 + t];
        ssni[t] = sn[bi * 32 + t];
        scsj[t] = cs[bj * 32 + t];
        ssnj[t] = sn[bj * 32 + t];
    }
    __syncthreads();

    int tj  = t & 31;
    int ti0 = t >> 5;
    int swzi = (ti0 & 7) << 2;   // == ((ti0+8r)&7)<<2 for all r
    int swzj = (tj & 7) << 2;

    float cjv = scsj[tj], sjv = ssnj[tj];
    float ct[4], st[4];
#pragma unroll
    for (int r = 0; r < 4; ++r) {
        int il = ti0 + 8 * r;
        float ci = scsi[il], si = ssni[il];
        ct[r] = fmaf(ci, cjv, si * sjv);                 // cos(2*pi*circdist)
        st[r] = fabsf(fmaf(si, cjv, -(ci * sjv)));       // sin(2*pi*circdist)
    }

    float acc1[4] = {0.f, 0.f, 0.f, 0.f};
    float acc2[4] = {0.f, 0.f, 0.f, 0.f};

#pragma unroll
    for (int hg = 0; hg < 16; ++hg) {
        const int h0 = hg * 4;
        f4 wc4 = *(const f4*)&sWc[h0];        // uniform addr -> broadcast
        f4 ws4 = *(const f4*)&sWs[h0];
        f4 w24 = *(const f4*)&sW2[h0];
        int ci_ = h0 ^ swzi;
        int cj_ = h0 ^ swzj;
        f4 aj4 = *(const f4*)&sAB[2][tj][cj_];
        f4 bj4 = *(const f4*)&sAB[3][tj][cj_];
#pragma unroll
        for (int r = 0; r < 4; ++r) {
            int il = ti0 + 8 * r;
            f4 ai4 = *(const f4*)&sAB[0][il][ci_];
            f4 bi4 = *(const f4*)&sAB[1][il][ci_];
#pragma unroll
            for (int k = 0; k < 4; ++k) {
                float d  = fmaf(ct[r], wc4[k], st[r] * ws4[k]);
                float p1 = ai4[k] + bj4[k] + d;   // orientation (i,j)
                float p2 = aj4[k] + bi4[k] + d;   // orientation (j,i)
                acc1[r] = fmaf(fmaxf(p1, 0.f), w24[k], acc1[r]);
                acc2[r] = fmaf(fmaxf(p2, 0.f), w24[k], acc2[r]);
            }
        }
    }

    float b2 = b2v[0];
#pragma unroll
    for (int r = 0; r < 4; ++r) {
        int il = ti0 + 8 * r;
        int gi = bi * 32 + il;
        int gj = bj * 32 + tj;
        float v = 0.5f * (acc1[r] + acc2[r]) + b2;
        if (gi == gj) v = -1e9f;
        out[(size_t)gi * N + gj] = v;
        tile[il][tj] = v;
    }

    if (bj > bi) {   // mirrored block, coalesced transposed write via LDS
        __syncthreads();
#pragma unroll
        for (int r = 0; r < 4; ++r) {
            int jl = ti0 + 8 * r;
            int grow = bj * 32 + jl;
            int gcol = bi * 32 + tj;
            out[(size_t)grow * N + gcol] = tile[tj][jl];
        }
    }
}

extern "C" void kernel_launch(void* const* d_in, const int* in_sizes, int n_in,
                              void* d_out, int out_size, void* d_ws, size_t ws_size,
                              hipStream_t stream) {
    const float* z  = (const float*)d_in[0];  // [32]
    const float* s  = (const float*)d_in[1];  // [N]
    const float* W1 = (const float*)d_in[2];  // [42,64]
    const float* b1 = (const float*)d_in[3];  // [64]
    const float* W2 = (const float*)d_in[4];  // [64]
    const float* b2 = (const float*)d_in[5];  // [1]
    int N = in_sizes[1];                      // 2048

    float* A2 = (float*)d_ws;                 // N*64 floats (swizzled)
    float* B2 = A2 + (size_t)N * 64;          // N*64 floats (swizzled)
    float* cs = B2 + (size_t)N * 64;          // N floats
    float* sn = cs + N;                       // N floats

    float* out = (float*)d_out;

    gd_precomp<<<(N * 64 + 255) / 256, 256, 0, stream>>>(
        z, s, W1, b1, A2, B2, cs, sn, N);

    int NB = N / 32;
    int nblk = NB * (NB + 1) / 2;
    gd_main<<<nblk, 256, 0, stream>>>(A2, B2, cs, sn, W1, W2, b2, out, N, NB);
}